// Round 4
// baseline (103.087 us; speedup 1.0000x reference)
//
#include <hip/hip_runtime.h>
#include <hip/hip_bf16.h>

// Problem constants
#define Dm   1024
#define Hh   16
#define HDq  64
#define DKV  512
#define HID  128
#define Bb   2
#define Ll   2048
#define Ff   32

typedef _Float16 half8 __attribute__((ext_vector_type(8)));
typedef _Float16 half4v __attribute__((ext_vector_type(4)));
typedef float f32x4 __attribute__((ext_vector_type(4)));

__device__ __forceinline__ float gelu_exact(float x) {
    return 0.5f * x * (1.0f + erff(x * 0.70710678118654752f));
}

// ---------------------------------------------------------------------------
// kprep:
//   blocks 0..127   : transpose+cvt Wv -> WT fp16 [512 n][1024 k]
//   blocks 128..159 : w1 hidden partials (b, which, jsplit) -> hid_part
//   blocks 160..175 : Qc partials (b, jsplit) -> qc_part
// ---------------------------------------------------------------------------
__global__ __launch_bounds__(256) void kprep(
        const float* __restrict__ h,
        const float* __restrict__ Wv, const float* __restrict__ Wq,
        const float* __restrict__ tw1, const float* __restrict__ dw1,
        _Float16* __restrict__ WT, float* __restrict__ hid_part,
        float* __restrict__ qc_part)
{
    const int bx = blockIdx.x, t = threadIdx.x;
    if (bx < 128) {
        __shared__ float T[64][65];
        const int kt = bx >> 3, nt = bx & 7;
        const int n0 = nt * 64, k0 = kt * 64;
        const int rr = t >> 4, cc4 = (t & 15) * 4;
#pragma unroll
        for (int i = 0; i < 4; ++i) {
            const int kl = i * 16 + rr;
            float4 v = *(const float4*)(Wv + (size_t)(k0 + kl) * DKV + n0 + cc4);
            T[kl][cc4 + 0] = v.x; T[kl][cc4 + 1] = v.y;
            T[kl][cc4 + 2] = v.z; T[kl][cc4 + 3] = v.w;
        }
        __syncthreads();
#pragma unroll
        for (int i = 0; i < 4; ++i) {
            const int nl = i * 16 + rr;
            half4v o;
            o[0] = (_Float16)T[cc4 + 0][nl]; o[1] = (_Float16)T[cc4 + 1][nl];
            o[2] = (_Float16)T[cc4 + 2][nl]; o[3] = (_Float16)T[cc4 + 3][nl];
            *(half4v*)(WT + (size_t)(n0 + nl) * Dm + k0 + cc4) = o;
        }
    } else if (bx < 160) {
        // hidden-layer partials over 128 h-elements for 128 hidden cols
        const int id = bx - 128;
        const int b = (id >> 4) & 1, which = (id >> 3) & 1, jsplit = id & 7;
        const float* w1 = which ? dw1 : tw1;
        __shared__ float hl[128];
        __shared__ float red[256];
        const float* hrow = h + ((size_t)b * Ll + (Ll - 1)) * Dm + jsplit * 128;
        if (t < 128) hl[t] = hrow[t];
        __syncthreads();
        const int col = t & 127, rg = t >> 7;
        const float* w1p = w1 + (size_t)(jsplit * 128 + rg + 1) * HID + col;
        float acc = 0.f;
#pragma unroll 8
        for (int p = 0; p < 64; ++p)
            acc += hl[p * 2 + rg] * w1p[(size_t)p * 2 * HID];
        red[t] = acc;
        __syncthreads();
        if (t < 128)
            hid_part[(((size_t)(b * 2 + which)) * 8 + jsplit) * HID + t] = red[t] + red[t + 128];
    } else {
        // Qc partials over Wq columns head*64+d (d<32)
        const int id = bx - 160;
        const int b = id >> 3, jsplit = id & 7;
        __shared__ float hl[128];
        const float* hrow = h + ((size_t)b * Ll + (Ll - 1)) * Dm + jsplit * 128;
        if (t < 128) hl[t] = hrow[t];
        __syncthreads();
        const int c0 = t, c1 = t + 256;
        const int colq0 = (c0 >> 5) * HDq + (c0 & 31);
        const int colq1 = (c1 >> 5) * HDq + (c1 & 31);
        const float* Wq0 = Wq + (size_t)(jsplit * 128) * Dm;
        float a0 = 0.f, a1 = 0.f;
#pragma unroll 8
        for (int j = 0; j < 128; ++j) {
            const float x = hl[j];
            a0 += x * Wq0[(size_t)j * Dm + colq0];
            a1 += x * Wq0[(size_t)j * Dm + colq1];
        }
        float* qp = qc_part + ((size_t)b * 8 + jsplit) * DKV;
        qp[c0] = a0;
        qp[c1] = a1;
    }
}

// ---------------------------------------------------------------------------
// k_wcomb: grid (Bb). finalize hidden -> tau, gh; delta matvec; combine.
// ---------------------------------------------------------------------------
__global__ __launch_bounds__(256) void k_wcomb(
        const float* __restrict__ mu, const float* __restrict__ sigma,
        const float* __restrict__ tw1, const float* __restrict__ tb1,
        const float* __restrict__ tw2, const float* __restrict__ tb2,
        const float* __restrict__ dw1, const float* __restrict__ db1,
        const float* __restrict__ dw2, const float* __restrict__ db2,
        const float* __restrict__ hid_part, const float* __restrict__ qc_part,
        float* __restrict__ w_comb)
{
    const int b = blockIdx.x;
    const int t = threadIdx.x;
    __shared__ float gh[HID];
    __shared__ float red[256];
    __shared__ float s_tau, s_smean, s_mmean;

    if (t == 0) {
        float s = 0.f;
        for (int f = 0; f < Ff; ++f) s += sigma[((size_t)b * Ll + (Ll - 1)) * Ff + f];
        s_smean = fmaxf(s / (float)Ff, 1e-6f);
    }
    if (t == 64) {
        float s = 0.f;
        for (int f = 0; f < Ff; ++f) s += mu[((size_t)b * Ll + (Ll - 1)) * Ff + f];
        s_mmean = s / (float)Ff;
    }
    red[t] = 0.f;
    __syncthreads();

    if (t < 128) {
        float a = tb1[t] + s_smean * tw1[t];
#pragma unroll
        for (int s = 0; s < 8; ++s)
            a += hid_part[(((size_t)(b * 2 + 0)) * 8 + s) * HID + t];
        red[t] = gelu_exact(a) * tw2[t];
    } else {
        const int hh = t - 128;
        float a = db1[hh] + s_mmean * dw1[hh];
#pragma unroll
        for (int s = 0; s < 8; ++s)
            a += hid_part[(((size_t)(b * 2 + 1)) * 8 + s) * HID + hh];
        gh[hh] = gelu_exact(a);
    }
    __syncthreads();
    for (int s = 64; s > 0; s >>= 1) {
        if (t < s) red[t] += red[t + s];
        __syncthreads();
    }
    if (t == 0) {
        float s = red[0] + tb2[0];
        s = fminf(fmaxf(s, -3.f), 3.f);
        s_tau = expf(s);
    }
    __syncthreads();

    const int c0 = t, c1 = t + 256;
    float d0 = db2[c0], d1 = db2[c1];
#pragma unroll 8
    for (int i = 0; i < HID; ++i) {
        const float x = gh[i];
        d0 += x * dw2[(size_t)i * DKV + c0];
        d1 += x * dw2[(size_t)i * DKV + c1];
    }
    d0 = fminf(fmaxf(d0, -5.f), 5.f);
    d1 = fminf(fmaxf(d1, -5.f), 5.f);
    float q0 = 0.f, q1 = 0.f;
#pragma unroll
    for (int s = 0; s < 8; ++s) {
        const float* qp = qc_part + ((size_t)b * 8 + s) * DKV;
        q0 += qp[c0];
        q1 += qp[c1];
    }
    const float inv_sqrt = 0.17677669529663687f;
    w_comb[(size_t)b * DKV + c0] = s_tau * q0 * inv_sqrt + d0;
    w_comb[(size_t)b * DKV + c1] = s_tau * q1 * inv_sqrt + d1;
}

// ---------------------------------------------------------------------------
// k_kw: kwh[b][h][j] = sum_{d<32} Wk[j][h*32+d] * w_comb[b][h*32+d]
// grid 32 blocks: blk = b*16 + jt. Each block: 64 j rows, lanes cover c-dim.
// ---------------------------------------------------------------------------
__global__ __launch_bounds__(256) void k_kw(
        const float* __restrict__ Wk, const float* __restrict__ w_comb,
        float* __restrict__ kwh_ws)
{
    const int blk = blockIdx.x;
    const int b = blk >> 4, jt = blk & 15;
    const int t = threadIdx.x;
    __shared__ float wc[DKV];
    {
        float2 v = *(const float2*)(w_comb + (size_t)b * DKV + t * 2);
        wc[t * 2] = v.x; wc[t * 2 + 1] = v.y;
    }
    __syncthreads();
    const int c0 = t * 2;
    const float w0 = wc[c0], w1 = wc[c0 + 1];
    const int hd = t >> 4;   // head for this 16-lane group
#pragma unroll 4
    for (int jj = 0; jj < 64; ++jj) {
        const int j = jt * 64 + jj;
        float2 kv = *(const float2*)(Wk + (size_t)j * DKV + c0);
        float p = kv.x * w0 + kv.y * w1;
        p += __shfl_xor(p, 1); p += __shfl_xor(p, 2);
        p += __shfl_xor(p, 4); p += __shfl_xor(p, 8);
        if ((t & 15) == 0)
            kwh_ws[((size_t)b * Hh + hd) * 1024 + j] = p;
    }
}

// ---------------------------------------------------------------------------
// k_kv: fp16 MFMA V-GEMM  V[4096 x 512] = h @ Wv, 64x128 tiles, grid (4, 64).
// ntile==0 blocks additionally compute logits = h @ kwh^T (fused, +1 MFMA/kstep).
// ---------------------------------------------------------------------------
__global__ __launch_bounds__(256) void k_kv(
        const float* __restrict__ hmat, const _Float16* __restrict__ WT,
        const float* __restrict__ kwh_ws,
        _Float16* __restrict__ V16, float* __restrict__ logits)
{
    __shared__ __align__(16) char smem[45312];
    _Float16* As = (_Float16*)smem;            // [64][32]
    _Float16* Bs = (_Float16*)(smem + 4096);   // [128][32]
    _Float16* Kw = (_Float16*)(smem + 12288);  // [16][1032] padded
    const int ntile = blockIdx.x, mtile = blockIdx.y;
    const int t = threadIdx.x;
    const int w = t >> 6, l = t & 63;
    const int m0 = mtile * 64, n0 = ntile * 128;
    const int wr = (w >> 1) * 32, wc = (w & 1) * 64;
    const int lrow = l & 15, kq = (l >> 4) * 8;
    const int b = mtile >> 5;
    const bool doLog = (ntile == 0);

    if (doLog) {
#pragma unroll
        for (int i = 0; i < 16; ++i) {
            const int flat = i * 256 + t;          // float4 index, 4096 total
            const int hh = flat >> 8, j4 = (flat & 255) * 4;
            float4 v = *(const float4*)(kwh_ws + ((size_t)b * Hh + hh) * 1024 + j4);
            _Float16* dst = Kw + hh * 1032 + j4;
            dst[0] = (_Float16)v.x; dst[1] = (_Float16)v.y;
            dst[2] = (_Float16)v.z; dst[3] = (_Float16)v.w;
        }
    }

    const int ar = t >> 2;            // A staging row 0..63
    const int ak = (t & 3) * 8;       // 8-float chunk
    const float* Ag = hmat + (size_t)(m0 + ar) * Dm + ak;
    const int nb0 = w * 32;

    f32x4 acc[2][4] = {};
    f32x4 lacc = {};

    for (int kt = 0; kt < 32; ++kt) {
        const int k0 = kt * 32;
        float4 a0 = *(const float4*)(Ag + k0);
        float4 a1 = *(const float4*)(Ag + k0 + 4);
#pragma unroll
        for (int cc = 0; cc < 2; ++cc) {
            const int nrow = nb0 + cc * 16 + (l >> 2);
            const _Float16* src = WT + (size_t)(n0 + nrow) * Dm + k0 + (l & 3) * 8;
            __builtin_amdgcn_global_load_lds(
                (const __attribute__((address_space(1))) unsigned int*)src,
                (__attribute__((address_space(3))) unsigned int*)(Bs + (nb0 + cc * 16) * 32),
                16, 0, 0);
        }
        half8 v0;
        v0[0] = (_Float16)a0.x; v0[1] = (_Float16)a0.y; v0[2] = (_Float16)a0.z; v0[3] = (_Float16)a0.w;
        v0[4] = (_Float16)a1.x; v0[5] = (_Float16)a1.y; v0[6] = (_Float16)a1.z; v0[7] = (_Float16)a1.w;
        *(half8*)(As + ar * 32 + ak) = v0;
        __syncthreads();
        half8 af[2], bf[4];
#pragma unroll
        for (int mf = 0; mf < 2; ++mf)
            af[mf] = *(const half8*)(As + (wr + mf * 16 + lrow) * 32 + kq);
#pragma unroll
        for (int nf = 0; nf < 4; ++nf)
            bf[nf] = *(const half8*)(Bs + (wc + nf * 16 + lrow) * 32 + kq);
#pragma unroll
        for (int mf = 0; mf < 2; ++mf)
#pragma unroll
            for (int nf = 0; nf < 4; ++nf)
                acc[mf][nf] = __builtin_amdgcn_mfma_f32_16x16x32_f16(af[mf], bf[nf], acc[mf][nf], 0, 0, 0);
        if (doLog) {
            half8 kf = *(const half8*)(Kw + lrow * 1032 + k0 + kq);
            lacc = __builtin_amdgcn_mfma_f32_16x16x32_f16(af[w & 1], kf, lacc, 0, 0, 0);
        }
        __syncthreads();
    }

    if (doLog) {
        // wave w covered logit rows m0 + w*16 .. +16, col = head = lrow
#pragma unroll
        for (int r = 0; r < 4; ++r) {
            const int row = m0 + w * 16 + (l >> 4) * 4 + r;
            float val = fminf(fmaxf(lacc[r], -50.f), 50.f);
            logits[((size_t)b * Hh + lrow) * Ll + (row & (Ll - 1))] = val;
        }
    }

    // V store via per-wave LDS bounce (reuses As/Bs/Kw space; all reads done)
    _Float16* Cs = (_Float16*)smem + w * 2048;   // [32][64] per wave
#pragma unroll
    for (int mf = 0; mf < 2; ++mf)
#pragma unroll
        for (int nf = 0; nf < 4; ++nf)
#pragma unroll
            for (int r = 0; r < 4; ++r)
                Cs[(mf * 16 + (l >> 4) * 4 + r) * 64 + nf * 16 + lrow] = (_Float16)acc[mf][nf][r];
    const int vc0 = n0 + wc;
#pragma unroll
    for (int p = 0; p < 4; ++p) {
        const int r = p * 8 + (l >> 3);
        const int ch = (l & 7) * 8;
        half8 v = *(const half8*)(Cs + r * 64 + ch);
        const int grow = m0 + wr + r;
        *(half8*)(V16 + (size_t)grow * DKV + vc0 + ch) = v;
    }
}

// ---------------------------------------------------------------------------
// k_attn: grid (8 splits, 32 bh). exp(logit-50) partial softmax + V sums
// ---------------------------------------------------------------------------
__global__ __launch_bounds__(256) void k_attn(
        const float* __restrict__ logits, const _Float16* __restrict__ V16,
        float* __restrict__ num_ws, float* __restrict__ den_ws)
{
    const int split = blockIdx.x, bh = blockIdx.y;
    const int b = bh >> 4, hd = bh & 15;
    const int t = threadIdx.x;
    __shared__ float p[256];
    __shared__ float red[256];
    __shared__ float part[8][32];
    const int l0 = split * 256;
    const float lv = logits[(size_t)bh * Ll + l0 + t];
    const float e = __expf(lv - 50.f);
    p[t] = e;
    red[t] = e;
    __syncthreads();
    for (int s = 128; s > 0; s >>= 1) {
        if (t < s) red[t] += red[t + s];
        __syncthreads();
    }
    if (t == 0) den_ws[bh * 8 + split] = red[0];
    const int kg = t >> 5, d = t & 31;
    const _Float16* Vb = V16 + (size_t)(b * Ll + l0 + kg * 32) * DKV + hd * 32 + d;
    float acc = 0.f;
#pragma unroll 4
    for (int j = 0; j < 32; ++j)
        acc += p[kg * 32 + j] * (float)Vb[(size_t)j * DKV];
    part[kg][d] = acc;
    __syncthreads();
    if (t < 32) {
        float s = 0.f;
#pragma unroll
        for (int g = 0; g < 8; ++g) s += part[g][t];
        num_ws[((size_t)bh * 8 + split) * 32 + t] = s;
    }
}

// ---------------------------------------------------------------------------
// k_out: partial out GEMM. grid (16 nt, 8 cs, 2 b); 64-col c-split each.
// ---------------------------------------------------------------------------
__global__ __launch_bounds__(256) void k_out(
        const float* __restrict__ num_ws, const float* __restrict__ den_ws,
        const float* __restrict__ Wo, float* __restrict__ out_part)
{
    const int nt = blockIdx.x, cs = blockIdx.y, b = blockIdx.z;
    const int t = threadIdx.x;
    __shared__ float op[64];
    __shared__ float red[256];
    if (t < 64) {
        const int c = cs * 64 + t;
        const int hd = c >> 5, d = c & 31;
        const int bh = b * Hh + hd;
        float s = 0.f, den = 0.f;
#pragma unroll
        for (int sp = 0; sp < 8; ++sp) {
            s += num_ws[((size_t)bh * 8 + sp) * 32 + d];
            den += den_ws[bh * 8 + sp];
        }
        op[t] = s / den;
    }
    __syncthreads();
    const int nl = t & 63, cg = t >> 6;
    const int n = nt * 64 + nl;
    float acc = 0.f;
#pragma unroll
    for (int i = 0; i < 16; ++i) {
        const int c = cs * 64 + cg * 16 + i;
        acc += op[cg * 16 + i] * Wo[(size_t)c * Dm + n];
    }
    red[t] = acc;
    __syncthreads();
    if (t < 64)
        out_part[(((size_t)b * 16 + nt) * 8 + cs) * 64 + nl] =
            red[t] + red[t + 64] + red[t + 128] + red[t + 192];
}

// ---------------------------------------------------------------------------
// k_fin: out[b][n] = bo[n] + sum_cs out_part. grid 8 x 256.
// ---------------------------------------------------------------------------
__global__ __launch_bounds__(256) void k_fin(
        const float* __restrict__ out_part, const float* __restrict__ bo,
        float* __restrict__ out)
{
    const int g = blockIdx.x * 256 + threadIdx.x;   // 0..2047
    const int b = g >> 10, n = g & 1023;
    const int nt = n >> 6, nl = n & 63;
    float s = bo[n];
#pragma unroll
    for (int cs = 0; cs < 8; ++cs)
        s += out_part[(((size_t)b * 16 + nt) * 8 + cs) * 64 + nl];
    out[g] = s;
}

// ---------------------------------------------------------------------------
extern "C" void kernel_launch(void* const* d_in, const int* in_sizes, int n_in,
                              void* d_out, int out_size, void* d_ws, size_t ws_size,
                              hipStream_t stream) {
    const float* h      = (const float*)d_in[0];
    const float* mu     = (const float*)d_in[1];
    const float* sigma  = (const float*)d_in[2];
    const float* Wq     = (const float*)d_in[3];
    const float* Wk     = (const float*)d_in[4];
    const float* Wv     = (const float*)d_in[5];
    const float* Wo     = (const float*)d_in[6];
    const float* bo     = (const float*)d_in[7];
    const float* tau_w1 = (const float*)d_in[8];
    const float* tau_b1 = (const float*)d_in[9];
    const float* tau_w2 = (const float*)d_in[10];
    const float* tau_b2 = (const float*)d_in[11];
    const float* del_w1 = (const float*)d_in[12];
    const float* del_b1 = (const float*)d_in[13];
    const float* del_w2 = (const float*)d_in[14];
    const float* del_b2 = (const float*)d_in[15];
    float* out = (float*)d_out;

    // workspace layout (~5.6 MB)
    _Float16* WT   = (_Float16*)d_ws;                       // 512*1024 fp16 = 1 MB
    _Float16* V16  = WT + (size_t)DKV * Dm;                 // 2*2048*512 fp16 = 4 MB
    float* logits  = (float*)(V16 + (size_t)Bb * Ll * DKV); // 65536 f32
    float* num_ws  = logits + (size_t)Bb * Hh * Ll;         // 8192 f32
    float* den_ws  = num_ws + 32 * 8 * 32;                  // 256 f32
    float* hid_part= den_ws + 256;                          // 4096 f32
    float* qc_part = hid_part + 4096;                       // 8192 f32
    float* w_comb  = qc_part + 8192;                        // 1024 f32
    float* kwh_ws  = w_comb + 1024;                         // 2*16*1024 = 32768 f32
    float* out_part= kwh_ws + (size_t)Bb * Hh * 1024;       // 16384 f32

    kprep<<<176, 256, 0, stream>>>(h, Wv, Wq, tau_w1, del_w1, WT, hid_part, qc_part);
    k_wcomb<<<Bb, 256, 0, stream>>>(mu, sigma, tau_w1, tau_b1, tau_w2, tau_b2,
                                    del_w1, del_b1, del_w2, del_b2,
                                    hid_part, qc_part, w_comb);
    k_kw<<<32, 256, 0, stream>>>(Wk, w_comb, kwh_ws);
    k_kv<<<dim3(4, 64), 256, 0, stream>>>(h, WT, kwh_ws, V16, logits);
    k_attn<<<dim3(8, 32), 256, 0, stream>>>(logits, V16, num_ws, den_ws);
    k_out<<<dim3(16, 8, Bb), 256, 0, stream>>>(num_ws, den_ws, Wo, out_part);
    k_fin<<<8, 256, 0, stream>>>(out_part, bo, out);
}

// Round 5
// 97.381 us; speedup vs baseline: 1.0586x; 1.0586x over previous
//
#include <hip/hip_runtime.h>
#include <hip/hip_bf16.h>

// Problem constants
#define Dm   1024
#define Hh   16
#define HDq  64
#define DKV  512
#define HID  128
#define Bb   2
#define Ll   2048
#define Ff   32

typedef _Float16 half8 __attribute__((ext_vector_type(8)));
typedef _Float16 half4v __attribute__((ext_vector_type(4)));
typedef float f32x4 __attribute__((ext_vector_type(4)));

#define GLOAD_LDS(gsrc, ldst) \
    __builtin_amdgcn_global_load_lds( \
        (const __attribute__((address_space(1))) unsigned int*)(gsrc), \
        (__attribute__((address_space(3))) unsigned int*)(ldst), 16, 0, 0)

__device__ __forceinline__ float gelu_exact(float x) {
    return 0.5f * x * (1.0f + erff(x * 0.70710678118654752f));
}

// Chunk format (shared by h16c / WTc / kwh16): 1KB chunk = 16 "rows" x 32 "k".
// chunk[l*8 + e] = M[rowbase + (l&15)][kbase + (l>>4)*8 + e]   (fp16)
// global_load_lds with per-lane src = chunk + l*16B stages it verbatim; the
// MFMA frag ds_read at lane*16B is then conflict-free.

// ---------------------------------------------------------------------------
// kprep:
//   bx 0..127   : transpose+cvt Wv -> WTc chunks (nb=0..31, kc=0..31)
//   bx 128..383 : h -> h16c chunks (rowblk = bx-128, kc=0..31)
//   bx 384..415 : w1 hidden partials -> hid_part
//   bx 416..431 : Qc partials -> qc_part
// ---------------------------------------------------------------------------
__global__ __launch_bounds__(256) void kprep(
        const float* __restrict__ h,
        const float* __restrict__ Wv, const float* __restrict__ Wq,
        const float* __restrict__ tw1, const float* __restrict__ dw1,
        _Float16* __restrict__ WTc, _Float16* __restrict__ h16c,
        float* __restrict__ hid_part, float* __restrict__ qc_part)
{
    __shared__ __align__(16) char sm[34 * 1024];
    const int bx = blockIdx.x, t = threadIdx.x;
    if (bx < 128) {
        float (*T)[65] = (float(*)[65])sm;           // T[k][n]
        const int kt = bx >> 3, nt = bx & 7;         // 64k x 64n tile
        const int n0 = nt * 64, k0 = kt * 64;
        const int rr = t >> 4, cc4 = (t & 15) * 4;
#pragma unroll
        for (int i = 0; i < 4; ++i) {
            const int kl = i * 16 + rr;
            float4 v = *(const float4*)(Wv + (size_t)(k0 + kl) * DKV + n0 + cc4);
            T[kl][cc4 + 0] = v.x; T[kl][cc4 + 1] = v.y;
            T[kl][cc4 + 2] = v.z; T[kl][cc4 + 3] = v.w;
        }
        __syncthreads();
#pragma unroll
        for (int s = 0; s < 2; ++s) {
            const int slot = s * 256 + t;
            const int cb = slot >> 6, lane = slot & 63;
            const int nb_l = cb >> 1, kc_l = cb & 1;
            const int n_l = nb_l * 16 + (lane & 15);
            const int k_l = kc_l * 32 + (lane >> 4) * 8;
            half8 v;
#pragma unroll
            for (int e = 0; e < 8; ++e) v[e] = (_Float16)T[k_l + e][n_l];
            const int chunk = (nt * 4 + nb_l) * 32 + (kt * 2 + kc_l);
            *(half8*)(WTc + (size_t)chunk * 512 + lane * 8) = v;
        }
    } else if (bx < 384) {
        _Float16 (*hl16)[1032] = (_Float16(*)[1032])sm;   // 16 x 1024 (+pad)
        const int rowblk = bx - 128;
        const float* src = h + (size_t)rowblk * 16 * Dm;
#pragma unroll 4
        for (int i = 0; i < 16; ++i) {
            float4 v = *(const float4*)(src + (size_t)i * Dm + t * 4);
            half4v o; o[0] = (_Float16)v.x; o[1] = (_Float16)v.y;
            o[2] = (_Float16)v.z; o[3] = (_Float16)v.w;
            *(half4v*)(&hl16[i][t * 4]) = o;
        }
        __syncthreads();
        const int w = t >> 6, l = t & 63;
        const int r = l & 15, q = l >> 4;
#pragma unroll
        for (int cc = 0; cc < 8; ++cc) {
            const int chunk = cc * 4 + w;
            half8 v = *(const half8*)(&hl16[r][chunk * 32 + q * 8]);
            *(half8*)(h16c + ((size_t)rowblk * 32 + chunk) * 512 + l * 8) = v;
        }
    } else if (bx < 416) {
        float* hl = (float*)sm;            // [128]
        float* red = hl + 128;             // [256]
        const int id = bx - 384;
        const int b = (id >> 4) & 1, which = (id >> 3) & 1, jsplit = id & 7;
        const float* w1 = which ? dw1 : tw1;
        const float* hrow = h + ((size_t)b * Ll + (Ll - 1)) * Dm + jsplit * 128;
        if (t < 128) hl[t] = hrow[t];
        __syncthreads();
        const int col = t & 127, rg = t >> 7;
        const float* w1p = w1 + (size_t)(jsplit * 128 + rg + 1) * HID + col;
        float acc = 0.f;
#pragma unroll 8
        for (int p = 0; p < 64; ++p)
            acc += hl[p * 2 + rg] * w1p[(size_t)p * 2 * HID];
        red[t] = acc;
        __syncthreads();
        if (t < 128)
            hid_part[(((size_t)(b * 2 + which)) * 8 + jsplit) * HID + t] = red[t] + red[t + 128];
    } else {
        float* hl = (float*)sm;            // [128]
        const int id = bx - 416;
        const int b = id >> 3, jsplit = id & 7;
        const float* hrow = h + ((size_t)b * Ll + (Ll - 1)) * Dm + jsplit * 128;
        if (t < 128) hl[t] = hrow[t];
        __syncthreads();
        const int c0 = t, c1 = t + 256;
        const int colq0 = (c0 >> 5) * HDq + (c0 & 31);
        const int colq1 = (c1 >> 5) * HDq + (c1 & 31);
        const float* Wq0 = Wq + (size_t)(jsplit * 128) * Dm;
        float a0 = 0.f, a1 = 0.f;
#pragma unroll 8
        for (int j = 0; j < 128; ++j) {
            const float x = hl[j];
            a0 += x * Wq0[(size_t)j * Dm + colq0];
            a1 += x * Wq0[(size_t)j * Dm + colq1];
        }
        float* qp = qc_part + ((size_t)b * 8 + jsplit) * DKV;
        qp[c0] = a0;
        qp[c1] = a1;
    }
}

// ---------------------------------------------------------------------------
// k_wcomb: grid (Bb). finalize hidden -> tau, gh; delta matvec; combine.
// ---------------------------------------------------------------------------
__global__ __launch_bounds__(256) void k_wcomb(
        const float* __restrict__ mu, const float* __restrict__ sigma,
        const float* __restrict__ tw1, const float* __restrict__ tb1,
        const float* __restrict__ tw2, const float* __restrict__ tb2,
        const float* __restrict__ dw1, const float* __restrict__ db1,
        const float* __restrict__ dw2, const float* __restrict__ db2,
        const float* __restrict__ hid_part, const float* __restrict__ qc_part,
        float* __restrict__ w_comb)
{
    const int b = blockIdx.x;
    const int t = threadIdx.x;
    __shared__ float gh[HID];
    __shared__ float red[256];
    __shared__ float s_tau, s_smean, s_mmean;

    if (t == 0) {
        float s = 0.f;
        for (int f = 0; f < Ff; ++f) s += sigma[((size_t)b * Ll + (Ll - 1)) * Ff + f];
        s_smean = fmaxf(s / (float)Ff, 1e-6f);
    }
    if (t == 64) {
        float s = 0.f;
        for (int f = 0; f < Ff; ++f) s += mu[((size_t)b * Ll + (Ll - 1)) * Ff + f];
        s_mmean = s / (float)Ff;
    }
    red[t] = 0.f;
    __syncthreads();

    if (t < 128) {
        float a = tb1[t] + s_smean * tw1[t];
#pragma unroll
        for (int s = 0; s < 8; ++s)
            a += hid_part[(((size_t)(b * 2 + 0)) * 8 + s) * HID + t];
        red[t] = gelu_exact(a) * tw2[t];
    } else {
        const int hh = t - 128;
        float a = db1[hh] + s_mmean * dw1[hh];
#pragma unroll
        for (int s = 0; s < 8; ++s)
            a += hid_part[(((size_t)(b * 2 + 1)) * 8 + s) * HID + hh];
        gh[hh] = gelu_exact(a);
    }
    __syncthreads();
    for (int s = 64; s > 0; s >>= 1) {
        if (t < s) red[t] += red[t + s];
        __syncthreads();
    }
    if (t == 0) {
        float s = red[0] + tb2[0];
        s = fminf(fmaxf(s, -3.f), 3.f);
        s_tau = expf(s);
    }
    __syncthreads();

    const int c0 = t, c1 = t + 256;
    float d0 = db2[c0], d1 = db2[c1];
#pragma unroll 8
    for (int i = 0; i < HID; ++i) {
        const float x = gh[i];
        d0 += x * dw2[(size_t)i * DKV + c0];
        d1 += x * dw2[(size_t)i * DKV + c1];
    }
    d0 = fminf(fmaxf(d0, -5.f), 5.f);
    d1 = fminf(fmaxf(d1, -5.f), 5.f);
    float q0 = 0.f, q1 = 0.f;
#pragma unroll
    for (int s = 0; s < 8; ++s) {
        const float* qp = qc_part + ((size_t)b * 8 + s) * DKV;
        q0 += qp[c0];
        q1 += qp[c1];
    }
    const float inv_sqrt = 0.17677669529663687f;
    w_comb[(size_t)b * DKV + c0] = s_tau * q0 * inv_sqrt + d0;
    w_comb[(size_t)b * DKV + c1] = s_tau * q1 * inv_sqrt + d1;
}

// ---------------------------------------------------------------------------
// k_kw: kwh[b][head][j] = sum_{d<32} Wk[j][head*32+d] * w_comb[b][head*32+d]
// grid 32 (b, jt: 64 j each) -> writes kwh16 chunks (b*32 + j/32).
// ---------------------------------------------------------------------------
__global__ __launch_bounds__(256) void k_kw(
        const float* __restrict__ Wk, const float* __restrict__ w_comb,
        _Float16* __restrict__ kwh16)
{
    const int blk = blockIdx.x;
    const int b = blk >> 4, jt = blk & 15;
    const int t = threadIdx.x;
    __shared__ float wc[DKV];
    __shared__ float kl[16][68];
    {
        float2 v = *(const float2*)(w_comb + (size_t)b * DKV + t * 2);
        wc[t * 2] = v.x; wc[t * 2 + 1] = v.y;
    }
    __syncthreads();
    const int c0 = t * 2;
    const float w0 = wc[c0], w1 = wc[c0 + 1];
    const int hd = t >> 4;
#pragma unroll 4
    for (int jj = 0; jj < 64; ++jj) {
        const int j = jt * 64 + jj;
        float2 kv = *(const float2*)(Wk + (size_t)j * DKV + c0);
        float p = kv.x * w0 + kv.y * w1;
        p += __shfl_xor(p, 1); p += __shfl_xor(p, 2);
        p += __shfl_xor(p, 4); p += __shfl_xor(p, 8);
        if ((t & 15) == 0) kl[hd][jj] = p;
    }
    __syncthreads();
    if (t < 128) {
        const int cl = t >> 6, lane = t & 63;
        const int head = lane & 15, jl = cl * 32 + (lane >> 4) * 8;
        half8 v;
#pragma unroll
        for (int e = 0; e < 8; ++e) v[e] = (_Float16)kl[head][jl + e];
        *(half8*)(kwh16 + ((size_t)(b * 32 + jt * 2 + cl)) * 512 + lane * 8) = v;
    }
}

// ---------------------------------------------------------------------------
// k_kv: fp16 MFMA V-GEMM  V[4096x512] = h16 @ Wv16, 64x128 tiles, 256 blocks.
// All staging via global_load_lds of 1KB lane-ordered chunks; 2-phase dbuf.
// ntile==0 blocks fuse logits = h @ kwh^T (one extra chunk + MFMA per step).
// ---------------------------------------------------------------------------
__global__ __launch_bounds__(256) void k_kv(
        const _Float16* __restrict__ h16c, const _Float16* __restrict__ WTc,
        const _Float16* __restrict__ kwh16,
        _Float16* __restrict__ V16, float* __restrict__ logits)
{
    __shared__ __align__(16) _Float16 sm16[13312];   // 26 KB
    _Float16* A0 = sm16;            // 4 chunks
    _Float16* B0 = sm16 + 2048;     // 8 chunks
    _Float16* K0 = sm16 + 6144;     // 1 chunk
    _Float16* A1 = sm16 + 6656;
    _Float16* B1 = sm16 + 8704;
    _Float16* K1 = sm16 + 12800;

    // bijective XCD swizzle: each XCD gets 8 contiguous mtiles (all 4 ntiles)
    const int hwid = blockIdx.x;                  // 256 blocks
    const int virt = (hwid & 7) * 32 + (hwid >> 3);
    const int ntile = virt & 3, mtile = virt >> 2;

    const int t = threadIdx.x;
    const int w = t >> 6, l = t & 63;
    const int m0 = mtile * 64, n0 = ntile * 128;
    const int wr = (w >> 1) * 32, wc = (w & 1) * 64;
    const int lrow = l & 15;
    const int b = mtile >> 5;
    const int mb0 = mtile * 4;
    const bool doLog = (ntile == 0);

    f32x4 acc[2][4] = {};
    f32x4 lacc = {};

    auto STAGEF = [&](int kt, _Float16* Ad, _Float16* Bd, _Float16* Kd) {
        const _Float16* sA = h16c + (((size_t)(mb0 + w)) * 32 + kt) * 512 + l * 8;
        GLOAD_LDS(sA, Ad + w * 512);
#pragma unroll
        for (int j = 0; j < 2; ++j) {
            const _Float16* sB = WTc + (((size_t)(ntile * 8 + w * 2 + j)) * 32 + kt) * 512 + l * 8;
            GLOAD_LDS(sB, Bd + (w * 2 + j) * 512);
        }
        if (doLog && w == 0) {
            const _Float16* sK = kwh16 + ((size_t)(b * 32 + kt)) * 512 + l * 8;
            GLOAD_LDS(sK, Kd);
        }
    };
    auto COMPUTE = [&](const _Float16* Ac, const _Float16* Bc, const _Float16* Kc) {
        half8 af[2], bf[4];
#pragma unroll
        for (int mf = 0; mf < 2; ++mf)
            af[mf] = *(const half8*)(Ac + ((w >> 1) * 2 + mf) * 512 + l * 8);
#pragma unroll
        for (int nf = 0; nf < 4; ++nf)
            bf[nf] = *(const half8*)(Bc + ((w & 1) * 4 + nf) * 512 + l * 8);
#pragma unroll
        for (int mf = 0; mf < 2; ++mf)
#pragma unroll
            for (int nf = 0; nf < 4; ++nf)
                acc[mf][nf] = __builtin_amdgcn_mfma_f32_16x16x32_f16(af[mf], bf[nf], acc[mf][nf], 0, 0, 0);
        if (doLog) {
            half8 kf = *(const half8*)(Kc + l * 8);
            lacc = __builtin_amdgcn_mfma_f32_16x16x32_f16(af[w & 1], kf, lacc, 0, 0, 0);
        }
    };

    STAGEF(0, A0, B0, K0);
    asm volatile("s_waitcnt vmcnt(0)" ::: "memory");
    __builtin_amdgcn_s_barrier();
    asm volatile("" ::: "memory");
    for (int kt = 0; kt < 32; kt += 2) {
        if (kt + 1 < 32) STAGEF(kt + 1, A1, B1, K1);
        COMPUTE(A0, B0, K0);
        asm volatile("s_waitcnt vmcnt(0)" ::: "memory");
        __builtin_amdgcn_s_barrier();
        asm volatile("" ::: "memory");
        if (kt + 2 < 32) STAGEF(kt + 2, A0, B0, K0);
        COMPUTE(A1, B1, K1);
        asm volatile("s_waitcnt vmcnt(0)" ::: "memory");
        __builtin_amdgcn_s_barrier();
        asm volatile("" ::: "memory");
    }

    if (doLog) {
#pragma unroll
        for (int r = 0; r < 4; ++r) {
            const int row = m0 + w * 16 + (l >> 4) * 4 + r;
            float val = fminf(fmaxf(lacc[r], -50.f), 50.f);
            logits[((size_t)b * Hh + lrow) * Ll + (row & (Ll - 1))] = val;
        }
    }

    // V store via per-wave LDS bounce, XOR-swizzled column chunks
    _Float16* Cs = sm16 + w * 2048;   // [32 rows][64 cols]
#pragma unroll
    for (int mf = 0; mf < 2; ++mf)
#pragma unroll
        for (int nf = 0; nf < 4; ++nf)
#pragma unroll
            for (int r = 0; r < 4; ++r) {
                const int row = mf * 16 + (l >> 4) * 4 + r;
                const int c8 = (nf * 2 + (lrow >> 3)) ^ (row & 7);
                Cs[row * 64 + c8 * 8 + (lrow & 7)] = (_Float16)acc[mf][nf][r];
            }
#pragma unroll
    for (int p = 0; p < 4; ++p) {
        const int r = p * 8 + (l >> 3);
        const int c8s = (l & 7) ^ (r & 7);
        half8 v = *(const half8*)(Cs + r * 64 + c8s * 8);
        *(half8*)(V16 + (size_t)(m0 + wr + r) * DKV + n0 + wc + (l & 7) * 8) = v;
    }
}

// ---------------------------------------------------------------------------
// k_attn: grid (8 splits, 32 bh). exp(logit-50) partial softmax + V sums
// ---------------------------------------------------------------------------
__global__ __launch_bounds__(256) void k_attn(
        const float* __restrict__ logits, const _Float16* __restrict__ V16,
        float* __restrict__ num_ws, float* __restrict__ den_ws)
{
    const int split = blockIdx.x, bh = blockIdx.y;
    const int b = bh >> 4, hd = bh & 15;
    const int t = threadIdx.x;
    __shared__ float p[256];
    __shared__ float red[256];
    __shared__ float part[8][32];
    const int l0 = split * 256;
    const float lv = logits[(size_t)bh * Ll + l0 + t];
    const float e = __expf(lv - 50.f);
    p[t] = e;
    red[t] = e;
    __syncthreads();
    for (int s = 128; s > 0; s >>= 1) {
        if (t < s) red[t] += red[t + s];
        __syncthreads();
    }
    if (t == 0) den_ws[bh * 8 + split] = red[0];
    const int kg = t >> 5, d = t & 31;
    const _Float16* Vb = V16 + (size_t)(b * Ll + l0 + kg * 32) * DKV + hd * 32 + d;
    float acc = 0.f;
#pragma unroll 4
    for (int j = 0; j < 32; ++j)
        acc += p[kg * 32 + j] * (float)Vb[(size_t)j * DKV];
    part[kg][d] = acc;
    __syncthreads();
    if (t < 32) {
        float s = 0.f;
#pragma unroll
        for (int g = 0; g < 8; ++g) s += part[g][t];
        num_ws[((size_t)bh * 8 + split) * 32 + t] = s;
    }
}

// ---------------------------------------------------------------------------
// k_out: partial out GEMM. grid (16 nt, 8 cs, 2 b)
// ---------------------------------------------------------------------------
__global__ __launch_bounds__(256) void k_out(
        const float* __restrict__ num_ws, const float* __restrict__ den_ws,
        const float* __restrict__ Wo, float* __restrict__ out_part)
{
    const int nt = blockIdx.x, cs = blockIdx.y, b = blockIdx.z;
    const int t = threadIdx.x;
    __shared__ float op[64];
    __shared__ float red[256];
    if (t < 64) {
        const int c = cs * 64 + t;
        const int hd = c >> 5, d = c & 31;
        const int bh = b * Hh + hd;
        float s = 0.f, den = 0.f;
#pragma unroll
        for (int sp = 0; sp < 8; ++sp) {
            s += num_ws[((size_t)bh * 8 + sp) * 32 + d];
            den += den_ws[bh * 8 + sp];
        }
        op[t] = s / den;
    }
    __syncthreads();
    const int nl = t & 63, cg = t >> 6;
    const int n = nt * 64 + nl;
    float acc = 0.f;
#pragma unroll
    for (int i = 0; i < 16; ++i) {
        const int c = cs * 64 + cg * 16 + i;
        acc += op[cg * 16 + i] * Wo[(size_t)c * Dm + n];
    }
    red[t] = acc;
    __syncthreads();
    if (t < 64)
        out_part[(((size_t)b * 16 + nt) * 8 + cs) * 64 + nl] =
            red[t] + red[t + 64] + red[t + 128] + red[t + 192];
}

// ---------------------------------------------------------------------------
// k_fin: out[b][n] = bo[n] + sum_cs out_part. grid 8 x 256.
// ---------------------------------------------------------------------------
__global__ __launch_bounds__(256) void k_fin(
        const float* __restrict__ out_part, const float* __restrict__ bo,
        float* __restrict__ out)
{
    const int g = blockIdx.x * 256 + threadIdx.x;   // 0..2047
    const int b = g >> 10, n = g & 1023;
    const int nt = n >> 6, nl = n & 63;
    float s = bo[n];
#pragma unroll
    for (int cs = 0; cs < 8; ++cs)
        s += out_part[(((size_t)b * 16 + nt) * 8 + cs) * 64 + nl];
    out[g] = s;
}

// ---------------------------------------------------------------------------
extern "C" void kernel_launch(void* const* d_in, const int* in_sizes, int n_in,
                              void* d_out, int out_size, void* d_ws, size_t ws_size,
                              hipStream_t stream) {
    const float* h      = (const float*)d_in[0];
    const float* mu     = (const float*)d_in[1];
    const float* sigma  = (const float*)d_in[2];
    const float* Wq     = (const float*)d_in[3];
    const float* Wk     = (const float*)d_in[4];
    const float* Wv     = (const float*)d_in[5];
    const float* Wo     = (const float*)d_in[6];
    const float* bo     = (const float*)d_in[7];
    const float* tau_w1 = (const float*)d_in[8];
    const float* tau_b1 = (const float*)d_in[9];
    const float* tau_w2 = (const float*)d_in[10];
    const float* tau_b2 = (const float*)d_in[11];
    const float* del_w1 = (const float*)d_in[12];
    const float* del_b1 = (const float*)d_in[13];
    const float* del_w2 = (const float*)d_in[14];
    const float* del_b2 = (const float*)d_in[15];
    float* out = (float*)d_out;

    // workspace layout (~13.5 MB)
    _Float16* h16c  = (_Float16*)d_ws;                       // 4M fp16 = 8 MB
    _Float16* WTc   = h16c + (size_t)4096 * 1024;            // 512K fp16 = 1 MB
    _Float16* V16   = WTc + (size_t)DKV * Dm;                // 2M fp16 = 4 MB
    _Float16* kwh16 = V16 + (size_t)Bb * Ll * DKV;           // 32K fp16 = 64 KB
    float* logits   = (float*)(kwh16 + (size_t)64 * 512);    // 65536 f32
    float* num_ws   = logits + (size_t)Bb * Hh * Ll;         // 8192 f32
    float* den_ws   = num_ws + 32 * 8 * 32;                  // 256 f32
    float* hid_part = den_ws + 256;                          // 4096 f32
    float* qc_part  = hid_part + 4096;                       // 8192 f32
    float* w_comb   = qc_part + 8192;                        // 1024 f32
    float* out_part = w_comb + 1024;                         // 16384 f32

    kprep<<<432, 256, 0, stream>>>(h, Wv, Wq, tau_w1, del_w1, WTc, h16c, hid_part, qc_part);
    k_wcomb<<<Bb, 256, 0, stream>>>(mu, sigma, tau_w1, tau_b1, tau_w2, tau_b2,
                                    del_w1, del_b1, del_w2, del_b2,
                                    hid_part, qc_part, w_comb);
    k_kw<<<32, 256, 0, stream>>>(Wk, w_comb, kwh16);
    k_kv<<<256, 256, 0, stream>>>(h16c, WTc, kwh16, V16, logits);
    k_attn<<<dim3(8, 32), 256, 0, stream>>>(logits, V16, num_ws, den_ws);
    k_out<<<dim3(16, 8, Bb), 256, 0, stream>>>(num_ws, den_ws, Wo, out_part);
    k_fin<<<8, 256, 0, stream>>>(out_part, bo, out);
}

// Round 6
// 62.875 us; speedup vs baseline: 1.6395x; 1.5488x over previous
//
#include <hip/hip_runtime.h>
#include <hip/hip_bf16.h>

// Problem constants
#define Dm   1024
#define Hh   16
#define HDq  64
#define DKV  512
#define HID  128
#define Bb   2
#define Ll   2048
#define Ff   32

typedef _Float16 half8 __attribute__((ext_vector_type(8)));
typedef float f32x4 __attribute__((ext_vector_type(4)));

__device__ __forceinline__ float gelu_exact(float x) {
    return 0.5f * x * (1.0f + erff(x * 0.70710678118654752f));
}

// ---------------------------------------------------------------------------
// kpart: grid 48.
//   bx 0..31 : w1 hidden partials (b, which, jsplit) -> hid_part
//   bx 32..47: Qc partials (b, jsplit) -> qc_part
// ---------------------------------------------------------------------------
__global__ __launch_bounds__(256) void kpart(
        const float* __restrict__ h, const float* __restrict__ Wq,
        const float* __restrict__ tw1, const float* __restrict__ dw1,
        float* __restrict__ hid_part, float* __restrict__ qc_part)
{
    const int bx = blockIdx.x, t = threadIdx.x;
    __shared__ float hl[128];
    __shared__ float red[256];
    if (bx < 32) {
        const int id = bx;
        const int b = (id >> 4) & 1, which = (id >> 3) & 1, jsplit = id & 7;
        const float* w1 = which ? dw1 : tw1;
        const float* hrow = h + ((size_t)b * Ll + (Ll - 1)) * Dm + jsplit * 128;
        if (t < 128) hl[t] = hrow[t];
        __syncthreads();
        const int col = t & 127, rg = t >> 7;
        const float* w1p = w1 + (size_t)(jsplit * 128 + rg + 1) * HID + col;
        float acc = 0.f;
#pragma unroll 8
        for (int p = 0; p < 64; ++p)
            acc += hl[p * 2 + rg] * w1p[(size_t)p * 2 * HID];
        red[t] = acc;
        __syncthreads();
        if (t < 128)
            hid_part[(((size_t)(b * 2 + which)) * 8 + jsplit) * HID + t] = red[t] + red[t + 128];
    } else {
        const int id = bx - 32;
        const int b = id >> 3, jsplit = id & 7;
        const float* hrow = h + ((size_t)b * Ll + (Ll - 1)) * Dm + jsplit * 128;
        if (t < 128) hl[t] = hrow[t];
        __syncthreads();
        const int c0 = t, c1 = t + 256;
        const int colq0 = (c0 >> 5) * HDq + (c0 & 31);
        const int colq1 = (c1 >> 5) * HDq + (c1 & 31);
        const float* Wq0 = Wq + (size_t)(jsplit * 128) * Dm;
        float a0 = 0.f, a1 = 0.f;
#pragma unroll 8
        for (int j = 0; j < 128; ++j) {
            const float x = hl[j];
            a0 += x * Wq0[(size_t)j * Dm + colq0];
            a1 += x * Wq0[(size_t)j * Dm + colq1];
        }
        float* qp = qc_part + ((size_t)b * 8 + jsplit) * DKV;
        qp[c0] = a0;
        qp[c1] = a1;
    }
}

// ---------------------------------------------------------------------------
// kwcomb: grid (8 cs, Bb). Redundant tau/gh per block; 64-c slice of
// w_comb[b][c] = tau*Qc/sqrt(32) + clip(delta, +-5).
// ---------------------------------------------------------------------------
__global__ __launch_bounds__(256) void kwcomb(
        const float* __restrict__ mu, const float* __restrict__ sigma,
        const float* __restrict__ tw1, const float* __restrict__ tb1,
        const float* __restrict__ tw2, const float* __restrict__ tb2,
        const float* __restrict__ dw1, const float* __restrict__ db1,
        const float* __restrict__ dw2, const float* __restrict__ db2,
        const float* __restrict__ hid_part, const float* __restrict__ qc_part,
        float* __restrict__ w_comb)
{
    const int cs = blockIdx.x, b = blockIdx.y;
    const int t = threadIdx.x;
    __shared__ float gh[HID];
    __shared__ float red[256];
    __shared__ float s_tau, s_sm, s_mm;

    if (t == 0) {
        float s = 0.f;
        for (int f = 0; f < Ff; ++f) s += sigma[((size_t)b * Ll + (Ll - 1)) * Ff + f];
        s_sm = fmaxf(s / (float)Ff, 1e-6f);
    }
    if (t == 64) {
        float s = 0.f;
        for (int f = 0; f < Ff; ++f) s += mu[((size_t)b * Ll + (Ll - 1)) * Ff + f];
        s_mm = s / (float)Ff;
    }
    __syncthreads();

    if (t < 128) {
        float a = tb1[t] + s_sm * tw1[t];
#pragma unroll
        for (int s = 0; s < 8; ++s)
            a += hid_part[(((size_t)(b * 2 + 0)) * 8 + s) * HID + t];
        red[t] = gelu_exact(a) * tw2[t];
    } else {
        const int hh = t - 128;
        float a = db1[hh] + s_mm * dw1[hh];
#pragma unroll
        for (int s = 0; s < 8; ++s)
            a += hid_part[(((size_t)(b * 2 + 1)) * 8 + s) * HID + hh];
        gh[hh] = gelu_exact(a);
        red[t] = 0.f;
    }
    __syncthreads();
    for (int s = 128; s > 0; s >>= 1) {
        if (t < s) red[t] += red[t + s];
        __syncthreads();
    }
    if (t == 0) {
        float s = red[0] + tb2[0];
        s_tau = expf(fminf(fmaxf(s, -3.f), 3.f));
    }
    __syncthreads();

    const int cl = t & 63, ih = t >> 6;
    const int c = cs * 64 + cl;
    float dacc = 0.f;
#pragma unroll 8
    for (int i = ih * 32; i < ih * 32 + 32; ++i)
        dacc += gh[i] * dw2[(size_t)i * DKV + c];
    red[t] = dacc;
    __syncthreads();
    if (t < 64) {
        const int cc = cs * 64 + t;
        float d = red[t] + red[t + 64] + red[t + 128] + red[t + 192] + db2[cc];
        d = fminf(fmaxf(d, -5.f), 5.f);
        float q = 0.f;
#pragma unroll
        for (int s = 0; s < 8; ++s)
            q += qc_part[((size_t)b * 8 + s) * DKV + cc];
        w_comb[(size_t)b * DKV + cc] = s_tau * q * 0.17677669529663687f + d;
    }
}

// ---------------------------------------------------------------------------
// kkw: kwh[b][head][j] = sum_{d<32} Wk[j][head*32+d] * w_comb[b][head*32+d]
// grid (32 jt, Bb): 32 j rows each -> one fp16 MFMA B-chunk
// chunk[lane*8+e] = kwh[head = lane&15][j_local = (lane>>4)*8 + e]
// ---------------------------------------------------------------------------
__global__ __launch_bounds__(256) void kkw(
        const float* __restrict__ Wk, const float* __restrict__ w_comb,
        _Float16* __restrict__ kwh16)
{
    const int jt = blockIdx.x, b = blockIdx.y;
    const int t = threadIdx.x;
    __shared__ float wc[DKV];
    __shared__ float kl[16][36];
    {
        float2 v = *(const float2*)(w_comb + (size_t)b * DKV + t * 2);
        wc[t * 2] = v.x; wc[t * 2 + 1] = v.y;
    }
    __syncthreads();
    const int c0 = t * 2;
    const float w0 = wc[c0], w1 = wc[c0 + 1];
    const int hd = t >> 4;
#pragma unroll 4
    for (int jj = 0; jj < 32; ++jj) {
        const int j = jt * 32 + jj;
        float2 kv = *(const float2*)(Wk + (size_t)j * DKV + c0);
        float p = kv.x * w0 + kv.y * w1;
        p += __shfl_xor(p, 1); p += __shfl_xor(p, 2);
        p += __shfl_xor(p, 4); p += __shfl_xor(p, 8);
        if ((t & 15) == 0) kl[hd][jj] = p;
    }
    __syncthreads();
    if (t < 64) {
        const int head = t & 15, jl = (t >> 4) * 8;
        half8 v;
#pragma unroll
        for (int e = 0; e < 8; ++e) v[e] = (_Float16)kl[head][jl + e];
        *(half8*)(kwh16 + ((size_t)(b * 32 + jt)) * 512 + t * 8) = v;
    }
}

// ---------------------------------------------------------------------------
// klogit: p[row][h] = exp(clip(sum_j h[row][j]*kwh[h][j], +-50) - 50)
// grid 256: 16 rows/block, 4 waves k-split (8 k-steps each), MFMA 16x16x32.
// Also den partials per (b, h, block).
// ---------------------------------------------------------------------------
__global__ __launch_bounds__(256) void klogit(
        const float* __restrict__ h, const _Float16* __restrict__ kwh16,
        float* __restrict__ p_arr, float* __restrict__ den_part)
{
    __shared__ __align__(16) _Float16 Kw[16384];   // 32 KB: kwh16[b]
    __shared__ float lred[4][16][16];
    __shared__ float pden[16][16];
    const int bx = blockIdx.x, t = threadIdx.x;
    const int w = t >> 6, l = t & 63;
    const int rows0 = bx * 16, b = bx >> 7;

#pragma unroll
    for (int i = 0; i < 8; ++i) {
        const int idx = i * 256 + t;
        *(half8*)(Kw + idx * 8) = *(const half8*)(kwh16 + (size_t)b * 16384 + idx * 8);
    }
    __syncthreads();

    f32x4 lacc = {};
    const float* ap = h + (size_t)(rows0 + (l & 15)) * Dm + (l >> 4) * 8;
#pragma unroll
    for (int kk = 0; kk < 8; ++kk) {
        const int kt = w * 8 + kk;
        float4 x0 = *(const float4*)(ap + kt * 32);
        float4 x1 = *(const float4*)(ap + kt * 32 + 4);
        half8 af;
        af[0] = (_Float16)x0.x; af[1] = (_Float16)x0.y; af[2] = (_Float16)x0.z; af[3] = (_Float16)x0.w;
        af[4] = (_Float16)x1.x; af[5] = (_Float16)x1.y; af[6] = (_Float16)x1.z; af[7] = (_Float16)x1.w;
        half8 kf = *(const half8*)(Kw + kt * 512 + l * 8);
        lacc = __builtin_amdgcn_mfma_f32_16x16x32_f16(af, kf, lacc, 0, 0, 0);
    }
#pragma unroll
    for (int r = 0; r < 4; ++r)
        lred[w][(l >> 4) * 4 + r][l & 15] = lacc[r];
    __syncthreads();

    const int row16 = t >> 4, head = t & 15;
    float val = lred[0][row16][head] + lred[1][row16][head]
              + lred[2][row16][head] + lred[3][row16][head];
    val = fminf(fmaxf(val, -50.f), 50.f);
    const float e = __expf(val - 50.f);
    p_arr[(size_t)(rows0 + row16) * 16 + head] = e;
    pden[row16][head] = e;
    __syncthreads();
    if (t < 16) {
        float s = 0.f;
#pragma unroll
        for (int r = 0; r < 16; ++r) s += pden[r][t];
        den_part[((size_t)b * 16 + t) * 128 + (bx & 127)] = s;
    }
}

// ---------------------------------------------------------------------------
// khbar: hbar_part[b][h][ls][j] = sum_{l in ls-range} p[l][h] * h[l][j]
// grid (8 jt, 16 ls, Bb): 128 l x 128 j per block.
// ---------------------------------------------------------------------------
__global__ __launch_bounds__(256) void khbar(
        const float* __restrict__ hmat, const float* __restrict__ p_arr,
        float* __restrict__ hbar_part)
{
    const int jt = blockIdx.x, ls = blockIdx.y, b = blockIdx.z;
    const int t = threadIdx.x;
    __shared__ float P[2048];    // [128 l][16 h]
#pragma unroll
    for (int i = 0; i < 2; ++i) {
        const int idx = i * 256 + t;
        *(float4*)(P + idx * 4) =
            *(const float4*)(p_arr + ((size_t)(b * Ll + ls * 128)) * 16 + idx * 4);
    }
    __syncthreads();
    const int hd = t & 15, jq = t >> 4;
    const float* hp = hmat + ((size_t)(b * Ll + ls * 128)) * Dm + jt * 128 + jq * 8;
    float4 a0 = {0.f, 0.f, 0.f, 0.f}, a1 = {0.f, 0.f, 0.f, 0.f};
#pragma unroll 4
    for (int l = 0; l < 128; ++l) {
        const float p = P[l * 16 + hd];
        float4 v0 = *(const float4*)(hp + (size_t)l * Dm);
        float4 v1 = *(const float4*)(hp + (size_t)l * Dm + 4);
        a0.x += p * v0.x; a0.y += p * v0.y; a0.z += p * v0.z; a0.w += p * v0.w;
        a1.x += p * v1.x; a1.y += p * v1.y; a1.z += p * v1.z; a1.w += p * v1.w;
    }
    float* dst = hbar_part + (((size_t)(b * 16 + hd)) * 16 + ls) * Dm + jt * 128 + jq * 8;
    *(float4*)dst = a0;
    *(float4*)(dst + 4) = a1;
}

// ---------------------------------------------------------------------------
// kopre: per (h, b): hbar[j] = sum_ls parts; den = sum den_part;
// opre[b][h*32+d] = (sum_j hbar[j]*Wv[j][h*32+d]) / den
// grid (16 h, Bb)
// ---------------------------------------------------------------------------
__global__ __launch_bounds__(256) void kopre(
        const float* __restrict__ hbar_part, const float* __restrict__ den_part,
        const float* __restrict__ Wv, float* __restrict__ opre)
{
    const int hd = blockIdx.x, b = blockIdx.y;
    const int t = threadIdx.x;
    __shared__ float hb[Dm];
    __shared__ float4 red4[256];
    __shared__ float dred[128];
    __shared__ float s_den;

    if (t < 128) dred[t] = den_part[((size_t)b * 16 + hd) * 128 + t];
    float4 a = {0.f, 0.f, 0.f, 0.f};
#pragma unroll
    for (int ls = 0; ls < 16; ++ls) {
        float4 v = *(const float4*)(hbar_part + (((size_t)(b * 16 + hd)) * 16 + ls) * Dm + t * 4);
        a.x += v.x; a.y += v.y; a.z += v.z; a.w += v.w;
    }
    *(float4*)(hb + t * 4) = a;
    __syncthreads();
    if (t < 64) dred[t] += dred[t + 64];
    __syncthreads();
    if (t < 32) dred[t] += dred[t + 32];
    __syncthreads();
    if (t == 0) {
        float s = 0.f;
        for (int i = 0; i < 32; ++i) s += dred[i];
        s_den = s;
    }
    __syncthreads();

    const int d4 = (t & 7) * 4, jq = t >> 3;
    float4 acc = {0.f, 0.f, 0.f, 0.f};
#pragma unroll 8
    for (int j = jq * 32; j < jq * 32 + 32; ++j) {
        const float x = hb[j];
        float4 wv = *(const float4*)(Wv + (size_t)j * DKV + hd * 32 + d4);
        acc.x += x * wv.x; acc.y += x * wv.y; acc.z += x * wv.z; acc.w += x * wv.w;
    }
    red4[t] = acc;
    __syncthreads();
    if (t < 8) {
        float4 s = {0.f, 0.f, 0.f, 0.f};
#pragma unroll
        for (int g = 0; g < 32; ++g) {
            float4 v = red4[g * 8 + t];
            s.x += v.x; s.y += v.y; s.z += v.z; s.w += v.w;
        }
        const float inv = 1.0f / s_den;
        s.x *= inv; s.y *= inv; s.z *= inv; s.w *= inv;
        *(float4*)(opre + ((size_t)b * Hh + hd) * 32 + t * 4) = s;
    }
}

// ---------------------------------------------------------------------------
// kout: out[b][n] = bo[n] + sum_c opre[b][c] * Wo[c][n]. grid (16 nt, Bb)
// ---------------------------------------------------------------------------
__global__ __launch_bounds__(256) void kout(
        const float* __restrict__ opre, const float* __restrict__ Wo,
        const float* __restrict__ bo, float* __restrict__ out)
{
    const int nt = blockIdx.x, b = blockIdx.y;
    const int t = threadIdx.x;
    __shared__ float op[DKV];
    __shared__ float red[256];
    if (t < 128)
        *(float4*)(op + t * 4) = *(const float4*)(opre + (size_t)b * DKV + t * 4);
    __syncthreads();
    const int nl = t & 63, cg = t >> 6;
    const int n = nt * 64 + nl;
    float acc = 0.f;
#pragma unroll 8
    for (int c = cg * 128; c < cg * 128 + 128; ++c)
        acc += op[c] * Wo[(size_t)c * Dm + n];
    red[t] = acc;
    __syncthreads();
    if (t < 64)
        out[(size_t)b * Dm + n] = bo[n] + red[t] + red[t + 64] + red[t + 128] + red[t + 192];
}

// ---------------------------------------------------------------------------
extern "C" void kernel_launch(void* const* d_in, const int* in_sizes, int n_in,
                              void* d_out, int out_size, void* d_ws, size_t ws_size,
                              hipStream_t stream) {
    const float* h      = (const float*)d_in[0];
    const float* mu     = (const float*)d_in[1];
    const float* sigma  = (const float*)d_in[2];
    const float* Wq     = (const float*)d_in[3];
    const float* Wk     = (const float*)d_in[4];
    const float* Wv     = (const float*)d_in[5];
    const float* Wo     = (const float*)d_in[6];
    const float* bo     = (const float*)d_in[7];
    const float* tau_w1 = (const float*)d_in[8];
    const float* tau_b1 = (const float*)d_in[9];
    const float* tau_w2 = (const float*)d_in[10];
    const float* tau_b2 = (const float*)d_in[11];
    const float* del_w1 = (const float*)d_in[12];
    const float* del_b1 = (const float*)d_in[13];
    const float* del_w2 = (const float*)d_in[14];
    const float* del_b2 = (const float*)d_in[15];
    float* out = (float*)d_out;

    // workspace (~2.5 MB)
    _Float16* kwh16  = (_Float16*)d_ws;                     // 2*32*512 = 32768 halfs
    float* p_arr     = (float*)(kwh16 + 32768);             // 4096*16 = 65536
    float* den_part  = p_arr + 65536;                       // 2*16*128 = 4096
    float* hid_part  = den_part + 4096;                     // 4096
    float* qc_part   = hid_part + 4096;                     // 8192
    float* w_comb    = qc_part + 8192;                      // 1024
    float* hbar_part = w_comb + 1024;                       // 2*16*16*1024 = 524288
    float* opre      = hbar_part + 524288;                  // 1024

    kpart<<<48, 256, 0, stream>>>(h, Wq, tau_w1, del_w1, hid_part, qc_part);
    kwcomb<<<dim3(8, Bb), 256, 0, stream>>>(mu, sigma, tau_w1, tau_b1, tau_w2, tau_b2,
                                            del_w1, del_b1, del_w2, del_b2,
                                            hid_part, qc_part, w_comb);
    kkw<<<dim3(32, Bb), 256, 0, stream>>>(Wk, w_comb, kwh16);
    klogit<<<256, 256, 0, stream>>>(h, kwh16, p_arr, den_part);
    khbar<<<dim3(8, 16, Bb), 256, 0, stream>>>(h, p_arr, hbar_part);
    kopre<<<dim3(16, Bb), 256, 0, stream>>>(hbar_part, den_part, Wv, opre);
    kout<<<dim3(16, Bb), 256, 0, stream>>>(opre, Wo, bo, out);
}